// Round 2
// baseline (282.180 us; speedup 1.0000x reference)
//
#include <hip/hip_runtime.h>

#define DD 256   // in_dim (= 2H)
#define HH 128   // per-branch out dim
#define CC 64    // n_class
#define BB 1024
#define SS1 25
#define SS2 10
#define NN 100000

typedef __attribute__((ext_vector_type(8))) short bf16x8;
typedef __attribute__((ext_vector_type(4))) float f32x4;

__device__ inline unsigned short f2b(float x) {
    union { float f; unsigned u; } v; v.f = x;
    unsigned r = (v.u + 0x7fffu + ((v.u >> 16) & 1u)) >> 16;
    return (unsigned short)r;
}
__device__ inline float b2f(unsigned u16) {
    union { unsigned u; float f; } v; v.u = u16 << 16;
    return v.f;
}

// ---------------------------------------------------------------------------
// W prep: [Wx1 | Wn1] fp32 [256][128]x2 -> bf16, MFMA B-fragment order:
//   frag = kc*16 + nt  (kc<8, nt<16; nt<8 -> Wx cols, nt>=8 -> Wn cols)
//   Wsw[(frag*64 + lane)*8 + j] = Wcat[kc*32 + (lane>>4)*8 + j][nt*16 + (lane&15)]
// ---------------------------------------------------------------------------
__global__ __launch_bounds__(256)
void prep_w(const float* __restrict__ Wx, const float* __restrict__ Wn,
            unsigned short* __restrict__ Wsw) {
    const int t    = blockIdx.x * 256 + threadIdx.x;   // 0..8191
    const int lane = t & 63;
    const int frag = t >> 6;                           // kc*16 + nt
    const int kc = frag >> 4, nt = frag & 15;
    const int quad = lane >> 4, lr = lane & 15;
    unsigned short v[8];
#pragma unroll
    for (int j = 0; j < 8; ++j) {
        int k = kc * 32 + quad * 8 + j;
        int n = nt * 16 + lr;                          // 0..255
        float w = (n < HH) ? Wx[k * HH + n] : Wn[k * HH + (n - HH)];
        v[j] = f2b(w);
    }
    ((uint4*)Wsw)[t] = *(uint4*)v;
}

// ---------------------------------------------------------------------------
// PQ = feat @ [Wx1 | Wn1] -> bf16 [NN][256]
// v6: v5's B-resident structure + RAW BARRIERS. __syncthreads() emits
// "s_waitcnt vmcnt(0)" before s_barrier (m97 behavior), which drained v5's
// prefetch every iteration -> serial load/compute, ~57 us. Here:
//   * barriers are __builtin_amdgcn_s_barrier() preceded by ONLY
//     "s_waitcnt lgkmcnt(0)" (LDS visibility). Prefetched global loads go
//     to private regs -> legal to stay in flight across the barrier; the
//     compiler emits a COUNTED vmcnt at next iteration's convert.
//   * single-buffered A-stage (sAO[0]) + separate O-stage (sAO[1]);
//     2 raw barriers/iter cover both WAR hazards:
//       - next convert overwrites sAO[0]: all MFMA ds_reads of sAO[0]
//         retire before barrier-2 (lgkm(0) covers them).
//       - pack overwrites sAO[1]: prior readback ds_reads retire before
//         next iteration's barrier-1.
// Steady state: 32 KB/block prefetch in flight (64 KB/CU >> 17 KB needed
// at the per-CU HBM share) -> BW-bound ~5-6 TB/s.
// ---------------------------------------------------------------------------
#define PQ_BLOCKS 512
#define PQ_TILES  (NN / 32)     // 3125, exact
#define AS 264                  // bf16 row stride (528 B)

__global__ __launch_bounds__(256, 2)
void pq_gemm(const float* __restrict__ feat,
             const unsigned short* __restrict__ Wsw,
             unsigned short* __restrict__ PQb) {
    __shared__ unsigned short sAO[2][32 * AS];   // [0]=A stage, [1]=O stage
    const int t    = threadIdx.x;
    const int w    = t >> 6, lane = t & 63;
    const int quad = lane >> 4, lr = lane & 15;

    // ---- B prologue: 32 fragments resident for this wave's 4 col-tiles
    bf16x8 B[8][4];
#pragma unroll
    for (int kc = 0; kc < 8; ++kc)
#pragma unroll
        for (int j = 0; j < 4; ++j)
            B[kc][j] = *(const bf16x8*)&Wsw[((kc * 16 + (w * 4 + j)) * 64 + lane) * 8];

    const int srow = t >> 5, sc = t & 31;

    // ---- prologue: issue tile-0 loads (8 float4 = 32 VGPR)
    float4 v[8];
    {
        const float* fb = feat + (long)blockIdx.x * 32 * DD + sc * 8;
#pragma unroll
        for (int i = 0; i < 4; ++i) {
            const float4* src = (const float4*)(fb + (long)(i * 8 + srow) * DD);
            v[2 * i]     = src[0];
            v[2 * i + 1] = src[1];
        }
    }

#pragma unroll 1
    for (int tile = blockIdx.x; tile < PQ_TILES; tile += PQ_BLOCKS) {
        // ---- 1) convert staged regs (counted vmcnt wait here) -> sAO[0]
#pragma unroll
        for (int i = 0; i < 4; ++i) {
            int row = i * 8 + srow;
            float4 a = v[2 * i], b = v[2 * i + 1];
            unsigned short w8[8] = { f2b(a.x), f2b(a.y), f2b(a.z), f2b(a.w),
                                     f2b(b.x), f2b(b.y), f2b(b.z), f2b(b.w) };
            *(uint4*)&sAO[0][row * AS + sc * 8] = *(uint4*)w8;
        }
        // ---- 2) issue NEXT tile's loads; stay in flight across barriers
        int tn = tile + PQ_BLOCKS;
        if (tn < PQ_TILES) {
            const float* fn = feat + (long)tn * 32 * DD + sc * 8;
#pragma unroll
            for (int i = 0; i < 4; ++i) {
                const float4* src = (const float4*)(fn + (long)(i * 8 + srow) * DD);
                v[2 * i]     = src[0];
                v[2 * i + 1] = src[1];
            }
        }
        // ---- 3) raw barrier: drain LDS only; vmcnt NOT drained
        asm volatile("s_waitcnt lgkmcnt(0)" ::: "memory");
        __builtin_amdgcn_s_barrier();

        // ---- 4) MFMA: pure LDS + resident-B
        f32x4 acc[2][4] = {};
#pragma unroll
        for (int kc = 0; kc < 8; ++kc) {
            bf16x8 a0 = *(const bf16x8*)&sAO[0][(lr)      * AS + kc * 32 + quad * 8];
            bf16x8 a1 = *(const bf16x8*)&sAO[0][(16 + lr) * AS + kc * 32 + quad * 8];
#pragma unroll
            for (int j = 0; j < 4; ++j) {
                acc[0][j] = __builtin_amdgcn_mfma_f32_16x16x32_bf16(a0, B[kc][j], acc[0][j], 0, 0, 0);
                acc[1][j] = __builtin_amdgcn_mfma_f32_16x16x32_bf16(a1, B[kc][j], acc[1][j], 0, 0, 0);
            }
        }
        // ---- 5) pack acc -> bf16 into sAO[1] (row=quad*4+r, col=lr)
#pragma unroll
        for (int rt = 0; rt < 2; ++rt)
#pragma unroll
            for (int j = 0; j < 4; ++j) {
                int col = (w * 4 + j) * 16 + lr;
#pragma unroll
                for (int r = 0; r < 4; ++r)
                    sAO[1][(rt * 16 + quad * 4 + r) * AS + col] = f2b(acc[rt][j][r]);
            }
        // ---- 6) raw barrier: pack visible; all sAO[0] reads retired
        asm volatile("s_waitcnt lgkmcnt(0)" ::: "memory");
        __builtin_amdgcn_s_barrier();

        // ---- 7) readback + coalesced store: 32 rows x 32 chunks of 16 B
#pragma unroll
        for (int i = 0; i < 4; ++i) {
            int id  = i * 256 + t;
            int row = id >> 5, ch = id & 31;
            uint4 d = *(uint4*)&sAO[1][row * AS + ch * 8];
            *(uint4*)&PQb[((long)tile * 32 + row) * DD + ch * 8] = d;
        }
    }
}

// ---------------------------------------------------------------------------
// build_gm (fuses old build_g1 + gm_mean; g1b never materialized):
//   gm[i] = (1/25) * sum_{s<25} relu([PQ[ids1[i*25+s]].X + bx1 |
//                                     (1/10) sum_j PQ[ids2[..]].N + bn1])
// 1 block per output row i. 8 half-wave slots; slot handles s = slot, +8, ...
// Cross-slot reduction via LDS. Saves 26 MB of HBM round-trip + 1 launch,
// and keeps the s-mean in fp32 (was bf16-rounded through g1b).
// ---------------------------------------------------------------------------
__global__ __launch_bounds__(256)
void build_gm(const unsigned short* __restrict__ PQb,
              const int* __restrict__ ids1, const int* __restrict__ ids2,
              const float* __restrict__ bx1, const float* __restrict__ bn1,
              float* __restrict__ gm) {
    __shared__ float sred[8][256];                 // 8 KB
    const int i    = blockIdx.x;
    const int t    = threadIdx.x;
    const int wv   = t >> 6;
    const int lane = t & 63;
    const int sub  = lane >> 5, lr = lane & 31;
    const int slot = wv * 2 + sub;                 // 0..7

    const float4 bx = *(const float4*)&bx1[lr * 4];
    const float4 bn = *(const float4*)&bn1[lr * 4];
    float4 xs = {0.f, 0.f, 0.f, 0.f}, ns = {0.f, 0.f, 0.f, 0.f};

#pragma unroll
    for (int it = 0; it < 4; ++it) {
        int s = slot + it * 8;
        if (s < SS1) {                             // uniform per half-wave
            int row  = i * SS1 + s;
            long xr  = (long)ids1[row];
            uint2 xv = *(const uint2*)&PQb[xr * DD + lr * 4];
            int myid = ids2[row * SS2 + (lr % SS2)];
            float4 acc = {0.f, 0.f, 0.f, 0.f};
#pragma unroll
            for (int j = 0; j < SS2; ++j) {
                long nr = (long)__shfl(myid, (lane & 32) + j);
                uint2 nv = *(const uint2*)&PQb[nr * DD + HH + lr * 4];
                acc.x += b2f(nv.x & 0xffff); acc.y += b2f(nv.x >> 16);
                acc.z += b2f(nv.y & 0xffff); acc.w += b2f(nv.y >> 16);
            }
            constexpr float inv = 1.f / SS2;
            xs.x += fmaxf(b2f(xv.x & 0xffff) + bx.x, 0.f);
            xs.y += fmaxf(b2f(xv.x >> 16)    + bx.y, 0.f);
            xs.z += fmaxf(b2f(xv.y & 0xffff) + bx.z, 0.f);
            xs.w += fmaxf(b2f(xv.y >> 16)    + bx.w, 0.f);
            ns.x += fmaxf(acc.x * inv + bn.x, 0.f);
            ns.y += fmaxf(acc.y * inv + bn.y, 0.f);
            ns.z += fmaxf(acc.z * inv + bn.z, 0.f);
            ns.w += fmaxf(acc.w * inv + bn.w, 0.f);
        }
    }
    *(float4*)&sred[slot][lr * 4]      = xs;
    *(float4*)&sred[slot][HH + lr * 4] = ns;
    __syncthreads();

    float r = 0.f;
#pragma unroll
    for (int k = 0; k < 8; ++k) r += sred[k][t];
    gm[(long)i * DD + t] = r * (1.f / SS1);
}

// ---------------------------------------------------------------------------
// tail_kernel (fuses old build_g0 + agg2 + head; g0/f0 never materialized):
// 128 blocks x 8 rows. Phase 0: build g0 rows into LDS (gathers) + load gm
// rows. Phase 1: F = [g0@Wx2+bx2 | gm@Wn2+bn2] in LDS. Phase 2: out = F@Wfc.
// All LDS matrix reads are wave-uniform (broadcast, conflict-free).
// ---------------------------------------------------------------------------
__global__ __launch_bounds__(256)
void tail_kernel(const unsigned short* __restrict__ PQb,
                 const int* __restrict__ ids0, const int* __restrict__ ids1,
                 const float* __restrict__ bx1, const float* __restrict__ bn1,
                 const float* __restrict__ gm,
                 const float* __restrict__ Wx2, const float* __restrict__ bx2,
                 const float* __restrict__ Wn2, const float* __restrict__ bn2,
                 const float* __restrict__ Wfc, const float* __restrict__ bfc,
                 float* __restrict__ out) {
    __shared__ float G[16][DD];    // rows 0-7: g0, rows 8-15: gm   (16 KB)
    __shared__ float F[8][DD];     // f0 rows                        (8 KB)
    const int r0   = blockIdx.x * 8;
    const int t    = threadIdx.x;
    const int wv   = t >> 6, lane = t & 63;
    const int sub  = lane >> 5, lr = lane & 31;
    const int row  = wv * 2 + sub;             // 0..7
    const int grow = r0 + row;

    // ---- phase 0a: g0 row -> G[row] (build_g0 body, LDS-resident)
    long xr  = (long)ids0[grow];
    uint2 xv = *(const uint2*)&PQb[xr * DD + lr * 4];
    int myid = ids1[(long)grow * SS1 + (lr % SS1)];
    float4 acc = {0.f, 0.f, 0.f, 0.f};
#pragma unroll 5
    for (int j = 0; j < SS1; ++j) {
        long nr = (long)__shfl(myid, (lane & 32) + j);
        uint2 nv = *(const uint2*)&PQb[nr * DD + HH + lr * 4];
        acc.x += b2f(nv.x & 0xffff); acc.y += b2f(nv.x >> 16);
        acc.z += b2f(nv.y & 0xffff); acc.w += b2f(nv.y >> 16);
    }
    {
        float4 bx = *(const float4*)&bx1[lr * 4];
        float4 bn = *(const float4*)&bn1[lr * 4];
        constexpr float inv = 1.f / SS1;
        float4 xo = { fmaxf(b2f(xv.x & 0xffff) + bx.x, 0.f),
                      fmaxf(b2f(xv.x >> 16)    + bx.y, 0.f),
                      fmaxf(b2f(xv.y & 0xffff) + bx.z, 0.f),
                      fmaxf(b2f(xv.y >> 16)    + bx.w, 0.f) };
        float4 no = { fmaxf(acc.x * inv + bn.x, 0.f),
                      fmaxf(acc.y * inv + bn.y, 0.f),
                      fmaxf(acc.z * inv + bn.z, 0.f),
                      fmaxf(acc.w * inv + bn.w, 0.f) };
        *(float4*)&G[row][lr * 4]      = xo;
        *(float4*)&G[row][HH + lr * 4] = no;
    }
    // ---- phase 0b: gm rows -> G[8..15]
#pragma unroll
    for (int i2 = 0; i2 < 2; ++i2) {
        int id = i2 * 256 + t;                 // 0..511
        int r = id >> 6, c4 = (id & 63) * 4;
        *(float4*)&G[8 + r][c4] = *(const float4*)(gm + (long)(r0 + r) * DD + c4);
    }
    __syncthreads();

    // ---- phase 1: F = [G0@Wx2+bx2 | Gm@Wn2+bn2]
    const int c  = t & 127;
    const int rh = t >> 7;                     // 0/1 -> rows rh*4..+4
#pragma unroll 1
    for (int by = 0; by < 2; ++by) {
        const float* __restrict__ W  = by ? Wn2 : Wx2;
        const float* __restrict__ bb = by ? bn2 : bx2;
        const int base = by * 8 + rh * 4;
        float a4[4] = {0.f, 0.f, 0.f, 0.f};
#pragma unroll 4
        for (int k = 0; k < DD; ++k) {
            float wk = W[k * HH + c];
#pragma unroll
            for (int r = 0; r < 4; ++r) a4[r] += G[base + r][k] * wk;
        }
        const float bias = bb[c];
#pragma unroll
        for (int r = 0; r < 4; ++r) F[rh * 4 + r][by * HH + c] = a4[r] + bias;
    }
    __syncthreads();

    // ---- phase 2: out = F @ Wfc + bfc
    const int hc = t & (CC - 1);
    const int rg = t >> 6;                     // 0..3 -> rows rg*2, rg*2+1
    float h0 = 0.f, h1 = 0.f;
#pragma unroll 4
    for (int k = 0; k < DD; ++k) {
        float wk = Wfc[k * CC + hc];
        h0 += F[rg * 2][k] * wk;
        h1 += F[rg * 2 + 1][k] * wk;
    }
    const float bias = bfc[hc];
    out[(long)(r0 + rg * 2) * CC + hc]     = h0 + bias;
    out[(long)(r0 + rg * 2 + 1) * CC + hc] = h1 + bias;
}

// ---------------------------------------------------------------------------
extern "C" void kernel_launch(void* const* d_in, const int* in_sizes, int n_in,
                              void* d_out, int out_size, void* d_ws, size_t ws_size,
                              hipStream_t stream) {
    const int*   ids0 = (const int*)d_in[0];
    const int*   ids1 = (const int*)d_in[1];
    const int*   ids2 = (const int*)d_in[2];
    const float* feat = (const float*)d_in[3];
    const float* Wx1  = (const float*)d_in[4];
    const float* bx1  = (const float*)d_in[5];
    const float* Wn1  = (const float*)d_in[6];
    const float* bn1  = (const float*)d_in[7];
    const float* Wx2  = (const float*)d_in[8];
    const float* bx2  = (const float*)d_in[9];
    const float* Wn2  = (const float*)d_in[10];
    const float* bn2  = (const float*)d_in[11];
    const float* Wfc  = (const float*)d_in[12];
    const float* bfc  = (const float*)d_in[13];
    float* out = (float*)d_out;

    float* wsf = (float*)d_ws;
    float* gm = wsf;  wsf += (long)BB * DD;              // 1 MB
    unsigned short* PQb = (unsigned short*)wsf;          // 51.2 MB
    unsigned short* Wsw = PQb + (long)NN * DD;           // 128 KB

    // 1) W prep (bf16 + B-fragment swizzle of [Wx1|Wn1])
    prep_w<<<32, 256, 0, stream>>>(Wx1, Wn1, Wsw);
    // 2) PQ = feat @ [Wx1|Wn1]  (bf16)                  [100000,256]
    pq_gemm<<<PQ_BLOCKS, 256, 0, stream>>>(feat, Wsw, PQb);
    // 3) gm = mean_s relu-agg (fused g1 + mean)         [1024,256]
    build_gm<<<BB, 256, 0, stream>>>(PQb, ids1, ids2, bx1, bn1, gm);
    // 4) g0 -> f0 -> out (fused build_g0 + agg2 + head) [1024,64]
    tail_kernel<<<BB / 8, 256, 0, stream>>>(PQb, ids0, ids1, bx1, bn1, gm,
                                            Wx2, bx2, Wn2, bn2, Wfc, bfc, out);
}

// Round 4
// 218.765 us; speedup vs baseline: 1.2899x; 1.2899x over previous
//
#include <hip/hip_runtime.h>

#define DD 256   // in_dim (= 2H)
#define HH 128   // per-branch out dim
#define CC 64    // n_class
#define BB 1024
#define SS1 25
#define SS2 10
#define NN 100000

typedef __attribute__((ext_vector_type(8))) short bf16x8;
typedef __attribute__((ext_vector_type(4))) float f32x4;

__device__ inline unsigned short f2b(float x) {
    union { float f; unsigned u; } v; v.f = x;
    unsigned r = (v.u + 0x7fffu + ((v.u >> 16) & 1u)) >> 16;
    return (unsigned short)r;
}
__device__ inline float b2f(unsigned u16) {
    union { unsigned u; float f; } v; v.u = u16 << 16;
    return v.f;
}

// ---------------------------------------------------------------------------
// W prep: [Wx1 | Wn1] fp32 [256][128]x2 -> bf16, MFMA B-fragment order:
//   frag = kc*16 + nt  (kc<8, nt<16; nt<8 -> Wx cols, nt>=8 -> Wn cols)
//   Wsw[(frag*64 + lane)*8 + j] = Wcat[kc*32 + (lane>>4)*8 + j][nt*16 + (lane&15)]
// ---------------------------------------------------------------------------
__global__ __launch_bounds__(256)
void prep_w(const float* __restrict__ Wx, const float* __restrict__ Wn,
            unsigned short* __restrict__ Wsw) {
    const int t    = blockIdx.x * 256 + threadIdx.x;   // 0..8191
    const int lane = t & 63;
    const int frag = t >> 6;                           // kc*16 + nt
    const int kc = frag >> 4, nt = frag & 15;
    const int quad = lane >> 4, lr = lane & 15;
    unsigned short v[8];
#pragma unroll
    for (int j = 0; j < 8; ++j) {
        int k = kc * 32 + quad * 8 + j;
        int n = nt * 16 + lr;                          // 0..255
        float w = (n < HH) ? Wx[k * HH + n] : Wn[k * HH + (n - HH)];
        v[j] = f2b(w);
    }
    ((uint4*)Wsw)[t] = *(uint4*)v;
}

// ---------------------------------------------------------------------------
// PQ = feat @ [Wx1 | Wn1] -> bf16 [NN][256]
// v6 (unchanged; passed verification in round 2): B-resident registers,
// single-stage LDS, RAW barriers (lgkmcnt-only drain) so the next-tile
// prefetch loads stay in flight across the MFMA+store phases; compiler
// emits counted vmcnt at the convert. 512 persistent blocks, 2/CU.
// ---------------------------------------------------------------------------
#define PQ_BLOCKS 512
#define PQ_TILES  (NN / 32)     // 3125, exact
#define AS 264                  // bf16 row stride (528 B)

__global__ __launch_bounds__(256, 2)
void pq_gemm(const float* __restrict__ feat,
             const unsigned short* __restrict__ Wsw,
             unsigned short* __restrict__ PQb) {
    __shared__ unsigned short sAO[2][32 * AS];   // [0]=A stage, [1]=O stage
    const int t    = threadIdx.x;
    const int w    = t >> 6, lane = t & 63;
    const int quad = lane >> 4, lr = lane & 15;

    // ---- B prologue: 32 fragments resident for this wave's 4 col-tiles
    bf16x8 B[8][4];
#pragma unroll
    for (int kc = 0; kc < 8; ++kc)
#pragma unroll
        for (int j = 0; j < 4; ++j)
            B[kc][j] = *(const bf16x8*)&Wsw[((kc * 16 + (w * 4 + j)) * 64 + lane) * 8];

    const int srow = t >> 5, sc = t & 31;

    // ---- prologue: issue tile-0 loads (8 float4 = 32 VGPR)
    float4 v[8];
    {
        const float* fb = feat + (long)blockIdx.x * 32 * DD + sc * 8;
#pragma unroll
        for (int i = 0; i < 4; ++i) {
            const float4* src = (const float4*)(fb + (long)(i * 8 + srow) * DD);
            v[2 * i]     = src[0];
            v[2 * i + 1] = src[1];
        }
    }

#pragma unroll 1
    for (int tile = blockIdx.x; tile < PQ_TILES; tile += PQ_BLOCKS) {
        // ---- 1) convert staged regs (counted vmcnt wait here) -> sAO[0]
#pragma unroll
        for (int i = 0; i < 4; ++i) {
            int row = i * 8 + srow;
            float4 a = v[2 * i], b = v[2 * i + 1];
            unsigned short w8[8] = { f2b(a.x), f2b(a.y), f2b(a.z), f2b(a.w),
                                     f2b(b.x), f2b(b.y), f2b(b.z), f2b(b.w) };
            *(uint4*)&sAO[0][row * AS + sc * 8] = *(uint4*)w8;
        }
        // ---- 2) issue NEXT tile's loads; stay in flight across barriers
        int tn = tile + PQ_BLOCKS;
        if (tn < PQ_TILES) {
            const float* fn = feat + (long)tn * 32 * DD + sc * 8;
#pragma unroll
            for (int i = 0; i < 4; ++i) {
                const float4* src = (const float4*)(fn + (long)(i * 8 + srow) * DD);
                v[2 * i]     = src[0];
                v[2 * i + 1] = src[1];
            }
        }
        // ---- 3) raw barrier: drain LDS only; vmcnt NOT drained
        asm volatile("s_waitcnt lgkmcnt(0)" ::: "memory");
        __builtin_amdgcn_s_barrier();

        // ---- 4) MFMA: pure LDS + resident-B
        f32x4 acc[2][4] = {};
#pragma unroll
        for (int kc = 0; kc < 8; ++kc) {
            bf16x8 a0 = *(const bf16x8*)&sAO[0][(lr)      * AS + kc * 32 + quad * 8];
            bf16x8 a1 = *(const bf16x8*)&sAO[0][(16 + lr) * AS + kc * 32 + quad * 8];
#pragma unroll
            for (int j = 0; j < 4; ++j) {
                acc[0][j] = __builtin_amdgcn_mfma_f32_16x16x32_bf16(a0, B[kc][j], acc[0][j], 0, 0, 0);
                acc[1][j] = __builtin_amdgcn_mfma_f32_16x16x32_bf16(a1, B[kc][j], acc[1][j], 0, 0, 0);
            }
        }
        // ---- 5) pack acc -> bf16 into sAO[1] (row=quad*4+r, col=lr)
#pragma unroll
        for (int rt = 0; rt < 2; ++rt)
#pragma unroll
            for (int j = 0; j < 4; ++j) {
                int col = (w * 4 + j) * 16 + lr;
#pragma unroll
                for (int r = 0; r < 4; ++r)
                    sAO[1][(rt * 16 + quad * 4 + r) * AS + col] = f2b(acc[rt][j][r]);
            }
        // ---- 6) raw barrier: pack visible; all sAO[0] reads retired
        asm volatile("s_waitcnt lgkmcnt(0)" ::: "memory");
        __builtin_amdgcn_s_barrier();

        // ---- 7) readback + coalesced store: 32 rows x 32 chunks of 16 B
#pragma unroll
        for (int i = 0; i < 4; ++i) {
            int id  = i * 256 + t;
            int row = id >> 5, ch = id & 31;
            uint4 d = *(uint4*)&sAO[1][row * AS + ch * 8];
            *(uint4*)&PQb[((long)tile * 32 + row) * DD + ch * 8] = d;
        }
    }
}

// ---------------------------------------------------------------------------
// megatail v3 (resubmitted unchanged — round-3 failure was harness-level,
// code audit found no OOB/hang candidate):
// ONE kernel, ONE block per output row (1024 blocks = 4/CU, ~16 waves/CU).
// Per block (row i):
//   phase A (8 half-wave slots): slot handles s = slot, +8, +16, +24 (<25):
//       xs  += relu(PQ[ids1].X + bx1)             (g1 x-part)
//       ns  += relu(mean_j PQ[ids2[s,j]].N + bn1) (g1 n-part)
//       g0n += PQ[ids1].N                         (g0 neighbor mean, raw)
//     cross-slot LDS reduce: gm = sum/25; g0 = [relu(PQ[ids0].X+bx1) |
//     relu(g0n/25 + bn1)].
//   phase B: F[c] = dot256(g0|gm, Wx2|Wn2 col c) + bias.
//   phase C: out[i] = F @ Wfc + bfc.
// ---------------------------------------------------------------------------
__global__ __launch_bounds__(256)
void megatail(const unsigned short* __restrict__ PQb,
              const int* __restrict__ ids0, const int* __restrict__ ids1,
              const int* __restrict__ ids2,
              const float* __restrict__ bx1, const float* __restrict__ bn1,
              const float* __restrict__ Wx2, const float* __restrict__ bx2,
              const float* __restrict__ Wn2, const float* __restrict__ bn2,
              const float* __restrict__ Wfc, const float* __restrict__ bfc,
              float* __restrict__ out) {
    __shared__ float sred[8][3 * HH];   // [slot][xs(128) | ns(128) | g0n(128)]
    __shared__ float g0L[DD];
    __shared__ float gmL[DD];
    __shared__ float FL[DD];
    __shared__ float sp[4][CC];
    const int i    = blockIdx.x;
    const int t    = threadIdx.x;
    const int wv   = t >> 6, lane = t & 63;
    const int sub  = lane >> 5, lr = lane & 31;
    const int slot = wv * 2 + sub;                 // 0..7

    const float4 bx = *(const float4*)&bx1[lr * 4];
    const float4 bn = *(const float4*)&bn1[lr * 4];
    float4 xs  = {0.f, 0.f, 0.f, 0.f};
    float4 ns  = {0.f, 0.f, 0.f, 0.f};
    float4 g0n = {0.f, 0.f, 0.f, 0.f};

    // ---- phase A: gathers (slot-parallel over the 25 s-values)
#pragma unroll
    for (int it = 0; it < 4; ++it) {
        int s = slot + it * 8;
        if (s < SS1) {                             // uniform per half-wave
            int row  = i * SS1 + s;
            long xr  = (long)ids1[row];
            uint2 xv  = *(const uint2*)&PQb[xr * DD + lr * 4];        // X half
            uint2 nv0 = *(const uint2*)&PQb[xr * DD + HH + lr * 4];   // N half
            int myid = ids2[row * SS2 + (lr % SS2)];
            float4 acc = {0.f, 0.f, 0.f, 0.f};
#pragma unroll
            for (int j = 0; j < SS2; ++j) {
                long nr = (long)__shfl(myid, (lane & 32) + j);
                uint2 nv = *(const uint2*)&PQb[nr * DD + HH + lr * 4];
                acc.x += b2f(nv.x & 0xffff); acc.y += b2f(nv.x >> 16);
                acc.z += b2f(nv.y & 0xffff); acc.w += b2f(nv.y >> 16);
            }
            constexpr float inv2 = 1.f / SS2;
            xs.x += fmaxf(b2f(xv.x & 0xffff) + bx.x, 0.f);
            xs.y += fmaxf(b2f(xv.x >> 16)    + bx.y, 0.f);
            xs.z += fmaxf(b2f(xv.y & 0xffff) + bx.z, 0.f);
            xs.w += fmaxf(b2f(xv.y >> 16)    + bx.w, 0.f);
            ns.x += fmaxf(acc.x * inv2 + bn.x, 0.f);
            ns.y += fmaxf(acc.y * inv2 + bn.y, 0.f);
            ns.z += fmaxf(acc.z * inv2 + bn.z, 0.f);
            ns.w += fmaxf(acc.w * inv2 + bn.w, 0.f);
            g0n.x += b2f(nv0.x & 0xffff); g0n.y += b2f(nv0.x >> 16);
            g0n.z += b2f(nv0.y & 0xffff); g0n.w += b2f(nv0.y >> 16);
        }
    }
    *(float4*)&sred[slot][lr * 4]            = xs;
    *(float4*)&sred[slot][HH + lr * 4]       = ns;
    *(float4*)&sred[slot][2 * HH + lr * 4]   = g0n;
    __syncthreads();

    // ---- phase A reduce: thread t owns column t
    {
        float rsum = 0.f;
#pragma unroll
        for (int k = 0; k < 8; ++k) rsum += sred[k][t];   // xs|ns layout = gm
        gmL[t] = rsum * (1.f / SS1);
        float g0v;
        if (t < HH) {            // wave-uniform (waves 0,1)
            unsigned short u = PQb[(long)ids0[i] * DD + t];
            g0v = fmaxf(b2f(u) + bx1[t], 0.f);
        } else {                 // waves 2,3
            float s2 = 0.f;
#pragma unroll
            for (int k = 0; k < 8; ++k) s2 += sred[k][2 * HH + (t - HH)];
            g0v = fmaxf(s2 * (1.f / SS1) + bn1[t - HH], 0.f);
        }
        g0L[t] = g0v;
    }
    __syncthreads();

    // ---- phase B: F[c] = dot(g0|gm, W2 col) + bias (c = t, wave-uniform)
    {
        const bool xhalf = (t < HH);
        const float* __restrict__ W    = xhalf ? Wx2 : Wn2;
        const float* __restrict__ srcL = xhalf ? g0L : gmL;
        const int cc = t & (HH - 1);
        float fa = 0.f;
#pragma unroll 8
        for (int k = 0; k < DD; ++k) fa += srcL[k] * W[k * HH + cc];
        fa += xhalf ? bx2[cc] : bn2[cc];
        FL[t] = fa;
    }
    __syncthreads();

    // ---- phase C: out = F @ Wfc + bfc
    {
        const int col = t & (CC - 1), q = t >> 6;
        float p = 0.f;
#pragma unroll 8
        for (int k = q * 64; k < q * 64 + 64; ++k) p += FL[k] * Wfc[k * CC + col];
        sp[q][col] = p;
    }
    __syncthreads();
    if (t < CC)
        out[(long)i * CC + t] = sp[0][t] + sp[1][t] + sp[2][t] + sp[3][t] + bfc[t];
}

// ---------------------------------------------------------------------------
extern "C" void kernel_launch(void* const* d_in, const int* in_sizes, int n_in,
                              void* d_out, int out_size, void* d_ws, size_t ws_size,
                              hipStream_t stream) {
    const int*   ids0 = (const int*)d_in[0];
    const int*   ids1 = (const int*)d_in[1];
    const int*   ids2 = (const int*)d_in[2];
    const float* feat = (const float*)d_in[3];
    const float* Wx1  = (const float*)d_in[4];
    const float* bx1  = (const float*)d_in[5];
    const float* Wn1  = (const float*)d_in[6];
    const float* bn1  = (const float*)d_in[7];
    const float* Wx2  = (const float*)d_in[8];
    const float* bx2  = (const float*)d_in[9];
    const float* Wn2  = (const float*)d_in[10];
    const float* bn2  = (const float*)d_in[11];
    const float* Wfc  = (const float*)d_in[12];
    const float* bfc  = (const float*)d_in[13];
    float* out = (float*)d_out;

    unsigned short* PQb = (unsigned short*)d_ws;         // 51.2 MB
    unsigned short* Wsw = PQb + (long)NN * DD;           // 128 KB

    // 1) W prep (bf16 + B-fragment swizzle of [Wx1|Wn1])
    prep_w<<<32, 256, 0, stream>>>(Wx1, Wn1, Wsw);
    // 2) PQ = feat @ [Wx1|Wn1]  (bf16)                  [100000,256]
    pq_gemm<<<PQ_BLOCKS, 256, 0, stream>>>(feat, Wsw, PQb);
    // 3) everything else, row-parallel                  [1024,64]
    megatail<<<BB, 256, 0, stream>>>(PQb, ids0, ids1, ids2, bx1, bn1,
                                     Wx2, bx2, Wn2, bn2, Wfc, bfc, out);
}

// Round 5
// 216.981 us; speedup vs baseline: 1.3005x; 1.0082x over previous
//
#include <hip/hip_runtime.h>

#define DD 256   // in_dim (= 2H)
#define HH 128   // per-branch out dim
#define CC 64    // n_class
#define BB 1024
#define SS1 25
#define SS2 10
#define NN 100000

typedef __attribute__((ext_vector_type(8))) short bf16x8;
typedef __attribute__((ext_vector_type(4))) float f32x4;

__device__ inline unsigned short f2b(float x) {
    union { float f; unsigned u; } v; v.f = x;
    unsigned r = (v.u + 0x7fffu + ((v.u >> 16) & 1u)) >> 16;
    return (unsigned short)r;
}
__device__ inline float b2f(unsigned u16) {
    union { unsigned u; float f; } v; v.u = u16 << 16;
    return v.f;
}

// ---------------------------------------------------------------------------
// W prep: [Wx1 | Wn1] fp32 [256][128]x2 -> bf16, MFMA B-fragment order:
//   frag = kc*16 + nt  (kc<8, nt<16; nt<8 -> Wx cols, nt>=8 -> Wn cols)
//   Wsw[(frag*64 + lane)*8 + j] = Wcat[kc*32 + (lane>>4)*8 + j][nt*16 + (lane&15)]
// ---------------------------------------------------------------------------
__global__ __launch_bounds__(256)
void prep_w(const float* __restrict__ Wx, const float* __restrict__ Wn,
            unsigned short* __restrict__ Wsw) {
    const int t    = blockIdx.x * 256 + threadIdx.x;   // 0..8191
    const int lane = t & 63;
    const int frag = t >> 6;                           // kc*16 + nt
    const int kc = frag >> 4, nt = frag & 15;
    const int quad = lane >> 4, lr = lane & 15;
    unsigned short v[8];
#pragma unroll
    for (int j = 0; j < 8; ++j) {
        int k = kc * 32 + quad * 8 + j;
        int n = nt * 16 + lr;                          // 0..255
        float w = (n < HH) ? Wx[k * HH + n] : Wn[k * HH + (n - HH)];
        v[j] = f2b(w);
    }
    ((uint4*)Wsw)[t] = *(uint4*)v;
}

// ---------------------------------------------------------------------------
// PQ = feat @ [Wx1 | Wn1] -> bf16 [NN][256]
// v7: v6 + DEPTH-2 register prefetch. v6's depth-1 meant the convert waited
// on loads issued only ~1000cy earlier (partial HBM-latency stall each tile,
// amplified by block lockstep). Two reg buffers va/vb; the unrolled-by-2
// loop keeps buffer parity compile-time (no scratch). conv(va) consumes
// loads issued TWO iterations ago (fully landed); issue(t+2*STRIDE) refills.
// Raw lgkmcnt-only barriers unchanged (prefetch stays in flight across
// them; compiler emits counted vmcnt at the convert).
// VGPR: B 128 + va/vb 64 + acc 32 + misc ~ 240 < 256 @ 2 waves/EU.
// ---------------------------------------------------------------------------
#define PQ_BLOCKS 512
#define PQ_TILES  (NN / 32)     // 3125, exact
#define AS 264                  // bf16 row stride (528 B)

#define PQ_ISSUE(VREG, TIDX)                                                  \
    {                                                                         \
        const float* fn_ = feat + (long)(TIDX) * 32 * DD + sc * 8;            \
        _Pragma("unroll")                                                     \
        for (int i_ = 0; i_ < 4; ++i_) {                                      \
            const float4* s_ = (const float4*)(fn_ + (long)(i_ * 8 + srow) * DD); \
            VREG[2 * i_]     = s_[0];                                         \
            VREG[2 * i_ + 1] = s_[1];                                         \
        }                                                                     \
    }

#define PQ_STEP(VREG)                                                         \
    {                                                                         \
        /* 1) convert staged regs (counted vmcnt wait here) -> sAO[0] */      \
        _Pragma("unroll")                                                     \
        for (int i_ = 0; i_ < 4; ++i_) {                                      \
            int row_ = i_ * 8 + srow;                                         \
            float4 a_ = VREG[2 * i_], b_ = VREG[2 * i_ + 1];                  \
            unsigned short w8_[8] = { f2b(a_.x), f2b(a_.y), f2b(a_.z), f2b(a_.w), \
                                      f2b(b_.x), f2b(b_.y), f2b(b_.z), f2b(b_.w) }; \
            *(uint4*)&sAO[0][row_ * AS + sc * 8] = *(uint4*)w8_;              \
        }                                                                     \
        /* 2) refill this buffer with tile+2*STRIDE */                        \
        {                                                                     \
            long t2_ = tile + 2L * PQ_BLOCKS;                                 \
            if (t2_ < PQ_TILES) PQ_ISSUE(VREG, t2_);                          \
        }                                                                     \
        /* 3) raw barrier: drain LDS only; vmcnt NOT drained */               \
        asm volatile("s_waitcnt lgkmcnt(0)" ::: "memory");                    \
        __builtin_amdgcn_s_barrier();                                         \
        /* 4) MFMA: pure LDS + resident-B */                                  \
        f32x4 acc[2][4] = {};                                                 \
        _Pragma("unroll")                                                     \
        for (int kc = 0; kc < 8; ++kc) {                                      \
            bf16x8 a0 = *(const bf16x8*)&sAO[0][(lr)      * AS + kc * 32 + quad * 8]; \
            bf16x8 a1 = *(const bf16x8*)&sAO[0][(16 + lr) * AS + kc * 32 + quad * 8]; \
            _Pragma("unroll")                                                 \
            for (int j = 0; j < 4; ++j) {                                     \
                acc[0][j] = __builtin_amdgcn_mfma_f32_16x16x32_bf16(a0, B[kc][j], acc[0][j], 0, 0, 0); \
                acc[1][j] = __builtin_amdgcn_mfma_f32_16x16x32_bf16(a1, B[kc][j], acc[1][j], 0, 0, 0); \
            }                                                                 \
        }                                                                     \
        /* 5) pack acc -> bf16 into sAO[1] (row=quad*4+r, col=lr) */          \
        _Pragma("unroll")                                                     \
        for (int rt = 0; rt < 2; ++rt)                                        \
            _Pragma("unroll")                                                 \
            for (int j = 0; j < 4; ++j) {                                     \
                int col_ = (w * 4 + j) * 16 + lr;                             \
                _Pragma("unroll")                                             \
                for (int r = 0; r < 4; ++r)                                   \
                    sAO[1][(rt * 16 + quad * 4 + r) * AS + col_] = f2b(acc[rt][j][r]); \
            }                                                                 \
        /* 6) raw barrier: pack visible; all sAO[0] reads retired */          \
        asm volatile("s_waitcnt lgkmcnt(0)" ::: "memory");                    \
        __builtin_amdgcn_s_barrier();                                         \
        /* 7) readback + coalesced store */                                   \
        _Pragma("unroll")                                                     \
        for (int i_ = 0; i_ < 4; ++i_) {                                      \
            int id_  = i_ * 256 + t;                                          \
            int row_ = id_ >> 5, ch_ = id_ & 31;                              \
            uint4 d_ = *(uint4*)&sAO[1][row_ * AS + ch_ * 8];                 \
            *(uint4*)&PQb[((long)tile * 32 + row_) * DD + ch_ * 8] = d_;      \
        }                                                                     \
    }

__global__ __launch_bounds__(256, 2)
void pq_gemm(const float* __restrict__ feat,
             const unsigned short* __restrict__ Wsw,
             unsigned short* __restrict__ PQb) {
    __shared__ unsigned short sAO[2][32 * AS];   // [0]=A stage, [1]=O stage
    const int t    = threadIdx.x;
    const int w    = t >> 6, lane = t & 63;
    const int quad = lane >> 4, lr = lane & 15;

    // ---- B prologue: 32 fragments resident for this wave's 4 col-tiles
    bf16x8 B[8][4];
#pragma unroll
    for (int kc = 0; kc < 8; ++kc)
#pragma unroll
        for (int j = 0; j < 4; ++j)
            B[kc][j] = *(const bf16x8*)&Wsw[((kc * 16 + (w * 4 + j)) * 64 + lane) * 8];

    const int srow = t >> 5, sc = t & 31;

    // ---- prologue: fill both prefetch buffers (depth 2)
    float4 va[8], vb[8];
    long tile = blockIdx.x;
    PQ_ISSUE(va, tile);
    if (tile + PQ_BLOCKS < PQ_TILES) PQ_ISSUE(vb, tile + PQ_BLOCKS);

    // every block has >= 6 tiles (3125/512), so both buffers are valid
    while (true) {
        PQ_STEP(va);
        tile += PQ_BLOCKS; if (tile >= PQ_TILES) break;
        PQ_STEP(vb);
        tile += PQ_BLOCKS; if (tile >= PQ_TILES) break;
    }
}

// ---------------------------------------------------------------------------
// megatail v4: one block per output row, now 512 threads (8 waves).
//   * phase A: 16 half-wave slots (was 8) -> serial s-depth 2 (was 4);
//     1024 blocks x 8 waves = 4 blocks/CU = 32 waves/CU (100% occupancy).
//   * phase B: 512 thr = 256 cols x 2 k-halves, LDS partial combine.
//   * phase C: 512 thr = 64 cols x 8 k-groups, LDS partial combine.
// ---------------------------------------------------------------------------
__global__ __launch_bounds__(512)
void megatail(const unsigned short* __restrict__ PQb,
              const int* __restrict__ ids0, const int* __restrict__ ids1,
              const int* __restrict__ ids2,
              const float* __restrict__ bx1, const float* __restrict__ bn1,
              const float* __restrict__ Wx2, const float* __restrict__ bx2,
              const float* __restrict__ Wn2, const float* __restrict__ bn2,
              const float* __restrict__ Wfc, const float* __restrict__ bfc,
              float* __restrict__ out) {
    __shared__ float sred[16][3 * HH];  // [slot][xs(128)|ns(128)|g0n(128)] 24.6KB
    __shared__ float g0L[DD];
    __shared__ float gmL[DD];
    __shared__ float FP[2][DD];         // phase-B partials
    __shared__ float FL[DD];
    __shared__ float sp[8][CC];         // phase-C partials
    const int i    = blockIdx.x;
    const int t    = threadIdx.x;                  // 0..511
    const int wv   = t >> 6, lane = t & 63;
    const int sub  = lane >> 5, lr = lane & 31;
    const int slot = wv * 2 + sub;                 // 0..15

    const float4 bx = *(const float4*)&bx1[lr * 4];
    const float4 bn = *(const float4*)&bn1[lr * 4];
    float4 xs  = {0.f, 0.f, 0.f, 0.f};
    float4 ns  = {0.f, 0.f, 0.f, 0.f};
    float4 g0n = {0.f, 0.f, 0.f, 0.f};

    // ---- phase A: gathers; slot handles s = slot and slot+16 (<25)
#pragma unroll
    for (int it = 0; it < 2; ++it) {
        int s = slot + it * 16;
        if (s < SS1) {                             // uniform per half-wave
            int row  = i * SS1 + s;
            long xr  = (long)ids1[row];
            uint2 xv  = *(const uint2*)&PQb[xr * DD + lr * 4];        // X half
            uint2 nv0 = *(const uint2*)&PQb[xr * DD + HH + lr * 4];   // N half
            int myid = ids2[row * SS2 + (lr % SS2)];
            float4 acc = {0.f, 0.f, 0.f, 0.f};
#pragma unroll
            for (int j = 0; j < SS2; ++j) {
                long nr = (long)__shfl(myid, (lane & 32) + j);
                uint2 nv = *(const uint2*)&PQb[nr * DD + HH + lr * 4];
                acc.x += b2f(nv.x & 0xffff); acc.y += b2f(nv.x >> 16);
                acc.z += b2f(nv.y & 0xffff); acc.w += b2f(nv.y >> 16);
            }
            constexpr float inv2 = 1.f / SS2;
            xs.x += fmaxf(b2f(xv.x & 0xffff) + bx.x, 0.f);
            xs.y += fmaxf(b2f(xv.x >> 16)    + bx.y, 0.f);
            xs.z += fmaxf(b2f(xv.y & 0xffff) + bx.z, 0.f);
            xs.w += fmaxf(b2f(xv.y >> 16)    + bx.w, 0.f);
            ns.x += fmaxf(acc.x * inv2 + bn.x, 0.f);
            ns.y += fmaxf(acc.y * inv2 + bn.y, 0.f);
            ns.z += fmaxf(acc.z * inv2 + bn.z, 0.f);
            ns.w += fmaxf(acc.w * inv2 + bn.w, 0.f);
            g0n.x += b2f(nv0.x & 0xffff); g0n.y += b2f(nv0.x >> 16);
            g0n.z += b2f(nv0.y & 0xffff); g0n.w += b2f(nv0.y >> 16);
        }
    }
    *(float4*)&sred[slot][lr * 4]          = xs;
    *(float4*)&sred[slot][HH + lr * 4]     = ns;
    *(float4*)&sred[slot][2 * HH + lr * 4] = g0n;
    __syncthreads();

    // ---- phase A reduce: t<256 -> gm col t; t>=256 -> g0 col (t-256)
    if (t < 256) {
        float r = 0.f;
#pragma unroll
        for (int k = 0; k < 16; ++k) r += sred[k][t];   // xs|ns layout = gm
        gmL[t] = r * (1.f / SS1);
    } else {
        const int c = t - 256;
        float v;
        if (c < HH) {            // wave-uniform (waves 4,5)
            unsigned short u = PQb[(long)ids0[i] * DD + c];
            v = fmaxf(b2f(u) + bx1[c], 0.f);
        } else {                 // waves 6,7
            float s2 = 0.f;
#pragma unroll
            for (int k = 0; k < 16; ++k) s2 += sred[k][2 * HH + (c - HH)];
            v = fmaxf(s2 * (1.f / SS1) + bn1[c - HH], 0.f);
        }
        g0L[c] = v;
    }
    __syncthreads();

    // ---- phase B: F[c] = dot256(g0|gm, W2 col c) + bias; k split in halves
    {
        const int c = t & 255, h = t >> 8;         // h = 0/1 (k-half)
        const bool xhalf = (c < HH);               // wave-uniform
        const float* __restrict__ W    = xhalf ? Wx2 : Wn2;
        const float* __restrict__ srcL = xhalf ? g0L : gmL;
        const int cc = c & (HH - 1);
        float fa = 0.f;
#pragma unroll 8
        for (int k = h * 128; k < h * 128 + 128; ++k) fa += srcL[k] * W[k * HH + cc];
        FP[h][c] = fa;
    }
    __syncthreads();
    if (t < 256)
        FL[t] = FP[0][t] + FP[1][t] + ((t < HH) ? bx2[t] : bn2[t - HH]);
    __syncthreads();

    // ---- phase C: out = F @ Wfc + bfc; 8 k-groups of 32
    {
        const int col = t & (CC - 1), q = t >> 6;  // q = 0..7
        float p = 0.f;
#pragma unroll 8
        for (int k = q * 32; k < q * 32 + 32; ++k) p += FL[k] * Wfc[k * CC + col];
        sp[q][col] = p;
    }
    __syncthreads();
    if (t < CC) {
        float r = bfc[t];
#pragma unroll
        for (int q = 0; q < 8; ++q) r += sp[q][t];
        out[(long)i * CC + t] = r;
    }
}

// ---------------------------------------------------------------------------
extern "C" void kernel_launch(void* const* d_in, const int* in_sizes, int n_in,
                              void* d_out, int out_size, void* d_ws, size_t ws_size,
                              hipStream_t stream) {
    const int*   ids0 = (const int*)d_in[0];
    const int*   ids1 = (const int*)d_in[1];
    const int*   ids2 = (const int*)d_in[2];
    const float* feat = (const float*)d_in[3];
    const float* Wx1  = (const float*)d_in[4];
    const float* bx1  = (const float*)d_in[5];
    const float* Wn1  = (const float*)d_in[6];
    const float* bn1  = (const float*)d_in[7];
    const float* Wx2  = (const float*)d_in[8];
    const float* bx2  = (const float*)d_in[9];
    const float* Wn2  = (const float*)d_in[10];
    const float* bn2  = (const float*)d_in[11];
    const float* Wfc  = (const float*)d_in[12];
    const float* bfc  = (const float*)d_in[13];
    float* out = (float*)d_out;

    unsigned short* PQb = (unsigned short*)d_ws;         // 51.2 MB
    unsigned short* Wsw = PQb + (long)NN * DD;           // 128 KB

    // 1) W prep (bf16 + B-fragment swizzle of [Wx1|Wn1])
    prep_w<<<32, 256, 0, stream>>>(Wx1, Wn1, Wsw);
    // 2) PQ = feat @ [Wx1|Wn1]  (bf16)                  [100000,256]
    pq_gemm<<<PQ_BLOCKS, 256, 0, stream>>>(feat, Wsw, PQb);
    // 3) everything else, row-parallel                  [1024,64]
    megatail<<<BB, 512, 0, stream>>>(PQb, ids0, ids1, ids2, bx1, bn1,
                                     Wx2, bx2, Wn2, bn2, Wfc, bfc, out);
}